// Round 9
// baseline (691.881 us; speedup 1.0000x reference)
//
#include <hip/hip_runtime.h>
#include <hip/hip_fp16.h>

constexpr int kNUser = 100000;
constexpr int kNItem = 50000;
constexpr int kN     = 150000;
constexpr int kEmb   = 64;
constexpr int kFeat  = 384;
constexpr int kNnz   = 2400000;
constexpr float kEps = 1e-8f;

// binned CSR build: 256 buckets of 586 rows; (rowrel<<18)|col packs into
// 28 bits (col < 2^18 = 262144, rowrel < 1024).
constexpr int kNBkt   = 256;
constexpr int kBR     = (kN + kNBkt - 1) / kNBkt;  // 586
constexpr int kChunkA = 4096;                      // edges per bucket WG
constexpr int kNWGA   = (kNnz + kChunkA - 1) / kChunkA;  // 586

// item-MLP MFMA geometry: 12 k-steps (K=384/32), 4 n-tiles (N=64/16)
constexpr int kKS     = kFeat / 32;   // 12
constexpr int kNT     = kEmb / 16;    // 4
constexpr int kWElems = kKS * kNT * 64 * 8;  // 24576 pre-split W frag elems

typedef __attribute__((ext_vector_type(8))) short short8v;   // 8 bf16 (4 VGPR)
typedef __attribute__((ext_vector_type(4))) float floatx4;

__device__ inline unsigned short f2bf(float f) {   // fp32 -> bf16 bits, RNE
    unsigned u = __float_as_uint(f);
    return (unsigned short)((u + 0x7FFFu + ((u >> 16) & 1u)) >> 16);
}
__device__ inline float bf2f(unsigned short h) {
    return __uint_as_float((unsigned)h << 16);
}

// ================= shared init kernels =================

__global__ void prompt_sum_k(const float* __restrict__ p, float* __restrict__ out) {
    int d = threadIdx.x;  // 64 threads
    float s = 0.f;
#pragma unroll
    for (int i = 0; i < 8; ++i) s += p[i * kEmb + d];
    out[d] = s;
}

// fp32-ego variant (fallback path only)
__global__ void user_ego_k(const float* __restrict__ uf, const float* __restrict__ ps,
                           float* __restrict__ ego) {
    int i = blockIdx.x * blockDim.x + threadIdx.x;
    if (i >= kNUser * kEmb) return;
    ego[i] = uf[i] + ps[i & 63];
}

// user rows -> egoh (fp16) + nrm directly; no fp32 ego buffer.
__global__ void user_egoh_k(const float* __restrict__ uf, const float* __restrict__ ps,
                            unsigned short* __restrict__ egoh, float* __restrict__ nrm) {
    int wid  = threadIdx.x >> 6;
    int lane = threadIdx.x & 63;
    int row  = blockIdx.x * 4 + wid;
    if (row >= kNUser) return;
    size_t idx = (size_t)row * kEmb + lane;
    float e = uf[idx] + ps[lane];
    __half h = __float2half_rn(e);
    egoh[idx] = *(unsigned short*)&h;
    float s = e * e;
#pragma unroll
    for (int o = 32; o >= 1; o >>= 1) s += __shfl_xor(s, o, 64);
    if (lane == 0) nrm[row] = sqrtf(s);
}

// ---- W pre-split: fragment-ordered bf16 hi/lo ----
__global__ void wsplit_k(const float* __restrict__ w, unsigned short* __restrict__ whi,
                         unsigned short* __restrict__ wlo) {
    int t = blockIdx.x * 256 + threadIdx.x;
    if (t >= kWElems) return;
    int j    = t & 7;
    int lane = (t >> 3) & 63;
    int nt   = (t >> 9) & 3;
    int ks   = t >> 11;
    int k = ks * 32 + (lane >> 4) * 8 + j;
    int n = nt * 16 + (lane & 15);
    float v = w[k * kEmb + n];
    unsigned short h = f2bf(v);
    whi[t] = h;
    wlo[t] = f2bf(v - bf2f(h));
}

// ---- item MLP via bf16x2-split MFMA; epilogue writes fp16 egoh + nrm ----
__global__ __launch_bounds__(256)
void item_ego_mfma_k(const float* __restrict__ itf, const unsigned short* __restrict__ whi,
                     const unsigned short* __restrict__ wlo, const float* __restrict__ b,
                     unsigned short* __restrict__ egoh, float* __restrict__ nrm) {
    int t    = threadIdx.x;
    int wid  = t >> 6;
    int lane = t & 63;
    int r0   = blockIdx.x * 64 + wid * 16;   // wave's first row
    int arow = r0 + (lane & 15);             // this lane's A row
    int kg   = lane >> 4;                    // k-group 0..3
    bool av  = arow < kNItem;                // uniform per wave (boundary % 16)
    const float* ap = itf + (size_t)(av ? arow : 0) * kFeat + kg * 8;

    const short8v* whv = (const short8v*)whi;
    const short8v* wlv = (const short8v*)wlo;

    floatx4 accH[kNT], accL[kNT];
#pragma unroll
    for (int nt = 0; nt < kNT; ++nt) {
        accH[nt] = (floatx4){0.f, 0.f, 0.f, 0.f};
        accL[nt] = (floatx4){0.f, 0.f, 0.f, 0.f};
    }

    for (int ks = 0; ks < kKS; ++ks) {
        const float4 z = make_float4(0.f, 0.f, 0.f, 0.f);
        float4 a0 = av ? *(const float4*)(ap + ks * 32)     : z;
        float4 a1 = av ? *(const float4*)(ap + ks * 32 + 4) : z;
        short8v ah, al;
#pragma unroll
        for (int j = 0; j < 8; ++j) {
            float f = (j < 4) ? ((const float*)&a0)[j] : ((const float*)&a1)[j - 4];
            unsigned short h = f2bf(f);
            ah[j] = (short)h;
            al[j] = (short)f2bf(f - bf2f(h));
        }
#pragma unroll
        for (int nt = 0; nt < kNT; ++nt) {
            short8v bh = whv[(ks * kNT + nt) * 64 + lane];
            short8v bl = wlv[(ks * kNT + nt) * 64 + lane];
            accH[nt] = __builtin_amdgcn_mfma_f32_16x16x32_bf16(ah, bh, accH[nt], 0, 0, 0);
            accL[nt] = __builtin_amdgcn_mfma_f32_16x16x32_bf16(ah, bl, accL[nt], 0, 0, 0);
            accL[nt] = __builtin_amdgcn_mfma_f32_16x16x32_bf16(al, bh, accL[nt], 0, 0, 0);
        }
    }

    int col0 = lane & 15;
    int rsub = (lane >> 4) * 4;
    float sq[4] = {0.f, 0.f, 0.f, 0.f};
#pragma unroll
    for (int nt = 0; nt < kNT; ++nt) {
        float bb = b[nt * 16 + col0];
#pragma unroll
        for (int r = 0; r < 4; ++r) {
            int row = r0 + rsub + r;
            float v = tanhf(accH[nt][r] + accL[nt][r] + bb);
            sq[r] = fmaf(v, v, sq[r]);
            if (row < kNItem) {
                __half h = __float2half_rn(v);
                egoh[(size_t)(kNUser + row) * kEmb + nt * 16 + col0] =
                    *(unsigned short*)&h;
            }
        }
    }
#pragma unroll
    for (int r = 0; r < 4; ++r) {
#pragma unroll
        for (int o = 1; o <= 8; o <<= 1) sq[r] += __shfl_xor(sq[r], o, 64);
        int row = r0 + rsub + r;
        if (col0 == 0 && row < kNItem) nrm[kNUser + row] = sqrtf(sq[r]);
    }
}

// ---- fallback-path item MLP (fp32 VALU, LDS-staged) ----
constexpr int kRW      = 16;   // rows per wave
constexpr int kRowsBlk = 64;   // rows per block (4 waves)
constexpr int kKc      = 32;   // K-chunk

__global__ __launch_bounds__(256, 2)
void item_ego_k(const float* __restrict__ itf, const float* __restrict__ w,
                const float* __restrict__ b, float* __restrict__ ego) {
    __shared__ float lds_a[kRowsBlk * kKc];  // 8 KB
    int t      = threadIdx.x;
    int wid    = t >> 6;
    int lane   = t & 63;
    int blk_r0 = blockIdx.x * kRowsBlk;

    float acc[kRW];
#pragma unroll
    for (int r = 0; r < kRW; ++r) acc[r] = 0.f;

    int srow = t >> 3;             // 0..31
    int scol = (t & 7) * 4;        // 0,4,..,28

    for (int kc = 0; kc < kFeat; kc += kKc) {
        __syncthreads();
        {
            const float4 z = make_float4(0.f, 0.f, 0.f, 0.f);
            int gr0 = blk_r0 + srow;
            int gr1 = gr0 + 32;
            float4 v0 = (gr0 < kNItem)
                ? *(const float4*)(itf + (size_t)gr0 * kFeat + kc + scol) : z;
            float4 v1 = (gr1 < kNItem)
                ? *(const float4*)(itf + (size_t)gr1 * kFeat + kc + scol) : z;
            *(float4*)(lds_a + srow * kKc + scol)        = v0;
            *(float4*)(lds_a + (srow + 32) * kKc + scol) = v1;
        }
        float wreg[kKc];
#pragma unroll
        for (int k = 0; k < kKc; ++k) wreg[k] = w[(kc + k) * kEmb + lane];
        __syncthreads();
#pragma unroll
        for (int r = 0; r < kRW; ++r) {
            const float4* av = (const float4*)(lds_a + (wid * kRW + r) * kKc);
#pragma unroll
            for (int q = 0; q < 8; ++q) {
                float4 a = av[q];
                acc[r] = fmaf(a.x, wreg[q * 4 + 0], acc[r]);
                acc[r] = fmaf(a.y, wreg[q * 4 + 1], acc[r]);
                acc[r] = fmaf(a.z, wreg[q * 4 + 2], acc[r]);
                acc[r] = fmaf(a.w, wreg[q * 4 + 3], acc[r]);
            }
        }
    }
    float bv = b[lane];
#pragma unroll
    for (int r = 0; r < kRW; ++r) {
        int row = blk_r0 + wid * kRW + r;
        if (row < kNItem)
            ego[(size_t)(kNUser + row) * kEmb + lane] = tanhf(acc[r] + bv);
    }
}

// ================= CSR build (bucket counting sort, no global row atomics) =================

__global__ __launch_bounds__(256)
void bcnt_k(const int* __restrict__ rows, int* __restrict__ bcnt) {
    __shared__ int cnt[kNBkt];
    int t  = threadIdx.x;
    int e0 = blockIdx.x * kChunkA;
    for (int i = t; i < kNBkt; i += 256) cnt[i] = 0;
    __syncthreads();
#pragma unroll
    for (int k = 0; k < kChunkA / 256; ++k) {
        int e = e0 + k * 256 + t;
        if (e < kNnz) atomicAdd(&cnt[rows[e] / kBR], 1);
    }
    __syncthreads();
    for (int i = t; i < kNBkt; i += 256)
        if (cnt[i]) atomicAdd(&bcnt[i], cnt[i]);
}

__global__ void bscan_k(const int* __restrict__ bcnt, int* __restrict__ bbase,
                        int* __restrict__ bfill) {
    __shared__ int sd[kNBkt];
    int t = threadIdx.x;
    int v = bcnt[t];
    sd[t] = v;
    __syncthreads();
#pragma unroll
    for (int off = 1; off < kNBkt; off <<= 1) {
        int u = (t >= off) ? sd[t - off] : 0;
        __syncthreads();
        sd[t] += u;
        __syncthreads();
    }
    bbase[t] = sd[t] - v;
    if (t == kNBkt - 1) bbase[kNBkt] = kNnz;
    bfill[t] = 0;
}

__global__ __launch_bounds__(256)
void bucket_k(const int* __restrict__ rows, const int* __restrict__ cols,
              const float* __restrict__ vals, const int* __restrict__ bbase,
              int* __restrict__ bfill, int2* __restrict__ tmp) {
    __shared__ int cnt[kNBkt];
    __shared__ int wgbase[kNBkt];
    int t  = threadIdx.x;
    int e0 = blockIdx.x * kChunkA;
    for (int i = t; i < kNBkt; i += 256) cnt[i] = 0;
    __syncthreads();
    int myb[kChunkA / 256];
    int myoff[kChunkA / 256];
#pragma unroll
    for (int k = 0; k < kChunkA / 256; ++k) {
        int e = e0 + k * 256 + t;                 // coalesced
        if (e < kNnz) {
            int b = rows[e] / kBR;                // const-divisor magic mul
            myb[k]   = b;
            myoff[k] = atomicAdd(&cnt[b], 1);     // LDS atomic
        } else {
            myb[k] = -1;
        }
    }
    __syncthreads();
    for (int i = t; i < kNBkt; i += 256)
        wgbase[i] = cnt[i] ? atomicAdd(&bfill[i], cnt[i]) : 0;
    __syncthreads();
#pragma unroll
    for (int k = 0; k < kChunkA / 256; ++k) {
        int b = myb[k];
        if (b < 0) continue;
        int e = e0 + k * 256 + t;
        int pos = bbase[b] + wgbase[b] + myoff[k];
        int rowrel = rows[e] - b * kBR;           // re-read, L2-hot
        tmp[pos] = make_int2((rowrel << 18) | cols[e], __float_as_int(vals[e]));
    }
}

__global__ __launch_bounds__(256)
void debucket2_k(const int2* __restrict__ tmp, const int* __restrict__ bbase,
                 int* __restrict__ rp, int2* __restrict__ csr) {
    __shared__ int rcnt[kBR];
    __shared__ int rbaseL[kBR];
    __shared__ int sd[256];
    int b  = blockIdx.x;
    int t  = threadIdx.x;
    int j0 = bbase[b];
    int j1 = bbase[b + 1];
    for (int i = t; i < kBR; i += 256) rcnt[i] = 0;
    __syncthreads();
    for (int j = j0 + t; j < j1; j += 256)
        atomicAdd(&rcnt[(unsigned)tmp[j].x >> 18], 1);
    __syncthreads();
    int base = t * 3;
    int c0 = (base     < kBR) ? rcnt[base]     : 0;
    int c1 = (base + 1 < kBR) ? rcnt[base + 1] : 0;
    int c2 = (base + 2 < kBR) ? rcnt[base + 2] : 0;
    int tsum = c0 + c1 + c2;
    sd[t] = tsum;
    __syncthreads();
#pragma unroll
    for (int off = 1; off < 256; off <<= 1) {
        int u = (t >= off) ? sd[t - off] : 0;
        __syncthreads();
        sd[t] += u;
        __syncthreads();
    }
    int g0 = j0 + sd[t] - tsum;
    if (base     < kBR) rbaseL[base]     = g0;
    if (base + 1 < kBR) rbaseL[base + 1] = g0 + c0;
    if (base + 2 < kBR) rbaseL[base + 2] = g0 + c0 + c1;
    __syncthreads();
    int rbaseG = b * kBR;
    for (int i = t; i < kBR; i += 256) {
        int r = rbaseG + i;
        if (r < kN) rp[r] = rbaseL[i];
    }
    if (b == kNBkt - 1 && t == 0) rp[kN] = kNnz;
    for (int i = t; i < kBR; i += 256) rcnt[i] = 0;
    __syncthreads();
    for (int j = j0 + t; j < j1; j += 256) {
        int2 e = tmp[j];
        int rr = (unsigned)e.x >> 18;
        int pos = rbaseL[rr] + atomicAdd(&rcnt[rr], 1);
        csr[pos] = make_int2(e.x & 0x3FFFF, e.y);
    }
}

// ============ fused layer: pull-SpMM + cosine reweight ============
// R11: 4 rows per wave, one per 16-lane group (qrow = lane>>4, sub = lane&15).
// Each group's 16 edges issue as 16 independent gather loads per wave (up
// from 4 in-flight) — attacks the measured latency x concurrency ceiling
// (~4 loads/wave x 24 waves/CU ~= 3.7 TB/s). No cross-q fold needed; every
// 16-lane group owns its row end-to-end. kN = 9375*16 exactly (full waves).
__global__ __launch_bounds__(256)
void layer_k(const int* __restrict__ rp, const int2* __restrict__ csr,
             const unsigned short* __restrict__ egoh, const float* __restrict__ nrm,
             const unsigned short* __restrict__ xin_h,
             unsigned short* __restrict__ xout_h,
             const unsigned short* __restrict__ xh1,
             const unsigned short* __restrict__ xh2,
             float* __restrict__ acc, int last) {
    int wid  = threadIdx.x >> 6;
    int lane = threadIdx.x & 63;
    int qrow = lane >> 4;       // which of the wave's 4 rows
    int sub  = lane & 15;       // dim quad: dims 4*sub .. 4*sub+3
    int row  = blockIdx.x * 16 + wid * 4 + qrow;
    if (row >= kN) return;
    int p0 = rp[row];
    int p1 = rp[row + 1];

    float4 s = make_float4(0.f, 0.f, 0.f, 0.f);
    for (int base = p0; base < p1; base += 16) {
        int2 e[16];
#pragma unroll
        for (int g = 0; g < 16; ++g) {
            int j  = base + g;
            bool v = j < p1;
            e[g] = csr[v ? j : p0];          // 16-lane broadcast load, 8 B
            if (!v) e[g].y = 0;              // w = 0.0f for padding edges
        }
        uint2 gv[16];
#pragma unroll
        for (int g = 0; g < 16; ++g)
            gv[g] = *(const uint2*)(xin_h + (size_t)e[g].x * kEmb + sub * 4);
#pragma unroll
        for (int g = 0; g < 16; ++g) {
            float w = __int_as_float(e[g].y);
            float2 f0 = __half22float2(*(const __half2*)&gv[g].x);
            float2 f1 = __half22float2(*(const __half2*)&gv[g].y);
            s.x = fmaf(w, f0.x, s.x);
            s.y = fmaf(w, f0.y, s.y);
            s.z = fmaf(w, f1.x, s.z);
            s.w = fmaf(w, f1.y, s.w);
        }
    }
    size_t idx = (size_t)row * kEmb + sub * 4;
    uint2 evu = *(const uint2*)(egoh + idx);
    float2 ea = __half22float2(*(const __half2*)&evu.x);
    float2 eb = __half22float2(*(const __half2*)&evu.y);
    float4 ev = make_float4(ea.x, ea.y, eb.x, eb.y);
    float d = s.x * ev.x + s.y * ev.y + s.z * ev.z + s.w * ev.w;
    float n = s.x * s.x + s.y * s.y + s.z * s.z + s.w * s.w;
    // reduce within the 16-lane group (xor of bits 0..3 stays in-group)
#pragma unroll
    for (int o = 1; o <= 8; o <<= 1) {
        d += __shfl_xor(d, o, 64);
        n += __shfl_xor(n, o, 64);
    }
    float wgt = d / fmaxf(sqrtf(n) * nrm[row], kEps);
    float4 xw = make_float4(wgt * s.x, wgt * s.y, wgt * s.z, wgt * s.w);
    if (!last) {
        __half2 o0 = __floats2half2_rn(xw.x, xw.y);
        __half2 o1 = __floats2half2_rn(xw.z, xw.w);
        uint2 st;
        st.x = *(unsigned*)&o0;
        st.y = *(unsigned*)&o1;
        *(uint2*)(xout_h + idx) = st;
    } else {
        // acc = ego + x1 + x2 + x3 + x4  (x3 == this layer's xin)
        uint2 a1 = *(const uint2*)(xh1 + idx);
        uint2 a2 = *(const uint2*)(xh2 + idx);
        uint2 a3 = *(const uint2*)(xin_h + idx);
        float2 f1a = __half22float2(*(const __half2*)&a1.x);
        float2 f1b = __half22float2(*(const __half2*)&a1.y);
        float2 f2a = __half22float2(*(const __half2*)&a2.x);
        float2 f2b = __half22float2(*(const __half2*)&a2.y);
        float2 f3a = __half22float2(*(const __half2*)&a3.x);
        float2 f3b = __half22float2(*(const __half2*)&a3.y);
        float4 out;
        out.x = ev.x + f1a.x + f2a.x + f3a.x + xw.x;
        out.y = ev.y + f1a.y + f2a.y + f3a.y + xw.y;
        out.z = ev.z + f1b.x + f2b.x + f3b.x + xw.z;
        out.w = ev.w + f1b.y + f2b.y + f3b.y + xw.w;
        *(float4*)(acc + idx) = out;
    }
}

// ================= fallback (atomic) kernels =================

__global__ void norm_init_full_k(const float* __restrict__ ego, float* __restrict__ nrm,
                                 float* __restrict__ x, float* __restrict__ acc) {
    int wid  = threadIdx.x >> 6;
    int lane = threadIdx.x & 63;
    int row  = blockIdx.x * 4 + wid;
    if (row >= kN) return;
    size_t idx = (size_t)row * kEmb + lane;
    float e = ego[idx];
    x[idx]   = e;
    acc[idx] = e;
    float s = e * e;
#pragma unroll
    for (int o = 32; o >= 1; o >>= 1) s += __shfl_xor(s, o, 64);
    if (lane == 0) nrm[row] = sqrtf(s);
}

__global__ void spmm_k(const int* __restrict__ rows, const int* __restrict__ cols,
                       const float* __restrict__ vals, const float* __restrict__ x,
                       float* __restrict__ y) {
    long long t = (long long)blockIdx.x * blockDim.x + threadIdx.x;
    int e = (int)(t >> 6);
    if (e >= kNnz) return;
    int lane = threadIdx.x & 63;
    atomicAdd(y + (size_t)rows[e] * kEmb + lane, vals[e] * x[(size_t)cols[e] * kEmb + lane]);
}

__global__ void weight_k(const float* __restrict__ ego, const float* __restrict__ nrm,
                         const float* __restrict__ y, float* __restrict__ x,
                         float* __restrict__ acc) {
    int wid  = threadIdx.x >> 6;
    int lane = threadIdx.x & 63;
    int row  = blockIdx.x * 4 + wid;
    if (row >= kN) return;
    size_t idx = (size_t)row * kEmb + lane;
    float yv = y[idx];
    float ev = ego[idx];
    float d = yv * ev;
    float n = yv * yv;
#pragma unroll
    for (int o = 32; o >= 1; o >>= 1) {
        d += __shfl_xor(d, o, 64);
        n += __shfl_xor(n, o, 64);
    }
    float w  = d / fmaxf(sqrtf(n) * nrm[row], kEps);
    float xw = w * yv;
    x[idx] = xw;
    acc[idx] += xw;
}

// ================= launch =================

extern "C" void kernel_launch(void* const* d_in, const int* in_sizes, int n_in,
                              void* d_out, int out_size, void* d_ws, size_t ws_size,
                              hipStream_t stream) {
    const float* user_fea = (const float*)d_in[0];
    const float* item_fea = (const float*)d_in[1];
    const float* prompt   = (const float*)d_in[2];
    const float* mlp_w    = (const float*)d_in[3];
    const float* mlp_b    = (const float*)d_in[4];
    const int*   adj_rows = (const int*)d_in[5];
    const int*   adj_cols = (const int*)d_in[6];
    const float* adj_vals = (const float*)d_in[7];
    float* acc = (float*)d_out;   // written once, by the last layer

    const size_t NE = (size_t)kN * kEmb;  // 9.6M
    float* ws = (float*)d_ws;

    // ---- workspace layout (4-byte units); shared prefix, then CSR-path ----
    size_t off = 0;
    float* f_ps  = ws + off; off += 64;
    float* f_nrm = ws + off; off += kN;
    size_t branch0 = off;
    // CSR path: fp16 buffers (xh1 doubles as bucket tmp)
    unsigned short* f_egoh = (unsigned short*)(ws + off); off += NE / 2;
    unsigned short* f_xh1  = (unsigned short*)(ws + off); off += NE / 2;
    unsigned short* f_xh2  = (unsigned short*)(ws + off); off += NE / 2;
    unsigned short* f_xh3  = (unsigned short*)(ws + off); off += NE / 2;
    int* row_ptr = (int*)(ws + off); off += kN + 1;
    int* bcnt    = (int*)(ws + off); off += kNBkt;
    int* bbase   = (int*)(ws + off); off += kNBkt + 1;
    int* bfill   = (int*)(ws + off); off += kNBkt;
    off = (off + 3) & ~(size_t)3;                   // 16B-align W frags
    unsigned short* whi = (unsigned short*)(ws + off); off += kWElems / 2;
    unsigned short* wlo = (unsigned short*)(ws + off); off += kWElems / 2;
    off = (off + 1) & ~(size_t)1;                   // 8B-align csr
    int2* csr = (int2*)(ws + off); off += (size_t)kNnz * 2;
    const bool use_csr = ws_size >= off * 4;

    prompt_sum_k<<<1, 64, 0, stream>>>(prompt, f_ps);

    if (use_csr) {
        // init: egoh + nrm directly (no fp32 ego buffer, no norm_init pass)
        user_egoh_k<<<(kNUser + 3) / 4, 256, 0, stream>>>(user_fea, f_ps,
                                                          f_egoh, f_nrm);
        wsplit_k<<<(kWElems + 255) / 256, 256, 0, stream>>>(mlp_w, whi, wlo);
        item_ego_mfma_k<<<(kNItem + 63) / 64, 256, 0, stream>>>(item_fea, whi, wlo,
                                                                mlp_b, f_egoh, f_nrm);

        // bucket staging aliases f_xh1 (free until layer 0 output)
        int2* tmp = (int2*)f_xh1;
        // ---- build CSR via bucket counting sort (no global row atomics) ----
        hipMemsetAsync(bcnt, 0, kNBkt * sizeof(int), stream);
        bcnt_k<<<kNWGA, 256, 0, stream>>>(adj_rows, bcnt);
        bscan_k<<<1, kNBkt, 0, stream>>>(bcnt, bbase, bfill);
        bucket_k<<<kNWGA, 256, 0, stream>>>(adj_rows, adj_cols, adj_vals,
                                            bbase, bfill, tmp);
        debucket2_k<<<kNBkt, 256, 0, stream>>>(tmp, bbase, row_ptr, csr);

        // ---- 4 fused layers: egoh -> xh1 -> xh2 -> xh3 -> acc ----
        const int grid = (kN + 15) / 16;   // 4 rows per wave, 16 per block
        layer_k<<<grid, 256, 0, stream>>>(row_ptr, csr, f_egoh, f_nrm,
                                          f_egoh, f_xh1, nullptr, nullptr,
                                          acc, 0);
        layer_k<<<grid, 256, 0, stream>>>(row_ptr, csr, f_egoh, f_nrm,
                                          f_xh1, f_xh2, nullptr, nullptr,
                                          acc, 0);
        layer_k<<<grid, 256, 0, stream>>>(row_ptr, csr, f_egoh, f_nrm,
                                          f_xh2, f_xh3, nullptr, nullptr,
                                          acc, 0);
        layer_k<<<grid, 256, 0, stream>>>(row_ptr, csr, f_egoh, f_nrm,
                                          f_xh3, nullptr, f_xh1, f_xh2,
                                          acc, 1);
    } else {
        // ---- fallback: atomic path (fp32 buffers carved past shared prefix) ----
        float* f_ego = ws + branch0;
        float* f_x   = f_ego + NE;
        float* f_y   = f_x + NE;
        user_ego_k<<<(kNUser * kEmb + 255) / 256, 256, 0, stream>>>(user_fea, f_ps,
                                                                    f_ego);
        item_ego_k<<<(kNItem + kRowsBlk - 1) / kRowsBlk, 256, 0, stream>>>(
            item_fea, mlp_w, mlp_b, f_ego);
        norm_init_full_k<<<(kN + 3) / 4, 256, 0, stream>>>(f_ego, f_nrm, f_x, acc);
        for (int l = 0; l < 4; ++l) {
            hipMemsetAsync(f_y, 0, NE * sizeof(float), stream);
            spmm_k<<<(int)(((long long)kNnz * 64 + 255) / 256), 256, 0, stream>>>(
                adj_rows, adj_cols, adj_vals, f_x, f_y);
            weight_k<<<(kN + 3) / 4, 256, 0, stream>>>(f_ego, f_nrm, f_y, f_x, acc);
        }
    }
}